// Round 1
// baseline (77.912 us; speedup 1.0000x reference)
//
#include <hip/hip_runtime.h>
#include <hip/hip_bf16.h>

// TensorDLT: closed-form 4-point homography (Heckbert square->quad) instead of
// per-batch 8x8 LU solve. Source corners fixed at (0,0),(127,0),(127,127),(0,127).
// offset[b, 8] = (du1,dv1,du2,dv2,du3,dv3,du4,dv4) scaled by MAX_PERTURBATION=32.
// Output H[b,3,3] row-major with H[2][2]=1 (matches reference h8=1 convention).

#define THREADS 256

__global__ __launch_bounds__(THREADS) void dlt_kernel(
    const float* __restrict__ off, float* __restrict__ out, int B) {
    __shared__ float lds[THREADS * 9];
    const int tid = threadIdx.x;

    for (int base = blockIdx.x * THREADS; base < B; base += gridDim.x * THREADS) {
        const int i = base + tid;
        float h[9];
        if (i < B) {
            // two float4 loads cover the 8 offsets (32B-aligned per item)
            const float4* p = (const float4*)off + (size_t)i * 2;
            const float4 o0 = p[0];
            const float4 o1 = p[1];
            const float M = 32.0f;
            // destination corners (x_k, y_k), k = 0..3 for src corners
            // (0,0),(127,0),(127,127),(0,127)
            const float x0 = 0.0f   + M * o0.x, y0 = 0.0f   + M * o0.y;
            const float x1 = 127.0f + M * o0.z, y1 = 0.0f   + M * o0.w;
            const float x2 = 127.0f + M * o1.x, y2 = 127.0f + M * o1.y;
            const float x3 = 0.0f   + M * o1.z, y3 = 127.0f + M * o1.w;

            // Heckbert: unit square (0,0),(1,0),(1,1),(0,1) -> (x0..x3,y0..y3)
            const float sx  = x0 - x1 + x2 - x3;
            const float sy  = y0 - y1 + y2 - y3;
            const float dx1 = x1 - x2, dy1 = y1 - y2;
            const float dx2 = x3 - x2, dy2 = y3 - y2;
            const float inv = 1.0f / (dx1 * dy2 - dy1 * dx2);  // |den| >= ~9000, safe
            const float g  = (sx * dy2 - sy * dx2) * inv;
            const float hh = (sy * dx1 - sx * dy1) * inv;
            const float a = x1 - x0 + g  * x1;
            const float b = x3 - x0 + hh * x3;
            const float d = y1 - y0 + g  * y1;
            const float e = y3 - y0 + hh * y3;

            // compose with src scaling diag(1/127, 1/127, 1): scale cols 0,1
            const float s = 1.0f / 127.0f;
            h[0] = a  * s;  h[1] = b  * s;  h[2] = x0;
            h[3] = d  * s;  h[4] = e  * s;  h[5] = y0;
            h[6] = g  * s;  h[7] = hh * s;  h[8] = 1.0f;
        } else {
            #pragma unroll
            for (int k = 0; k < 9; ++k) h[k] = 0.0f;
        }

        // stage to LDS (stride 9 is coprime with 32 banks -> <=2 lanes/bank, free)
        #pragma unroll
        for (int k = 0; k < 9; ++k) lds[tid * 9 + k] = h[k];
        __syncthreads();

        // coalesced stride-1 global stores of the block's contiguous 9*256 floats
        const long long obase = (long long)base * 9;
        const int remain = (B - base < THREADS ? B - base : THREADS) * 9;
        #pragma unroll
        for (int k = tid; k < remain; k += THREADS) {
            out[obase + k] = lds[k];
        }
        __syncthreads();
    }
}

extern "C" void kernel_launch(void* const* d_in, const int* in_sizes, int n_in,
                              void* d_out, int out_size, void* d_ws, size_t ws_size,
                              hipStream_t stream) {
    const float* off = (const float*)d_in[0];
    float* out = (float*)d_out;
    const int B = in_sizes[0] / 8;  // 524288
    int blocks = (B + THREADS - 1) / THREADS;  // 2048 -> 8 blocks/CU
    if (blocks > 8192) blocks = 8192;
    dlt_kernel<<<blocks, THREADS, 0, stream>>>(off, out, B);
}

// Round 2
// 76.033 us; speedup vs baseline: 1.0247x; 1.0247x over previous
//
#include <hip/hip_runtime.h>
#include <hip/hip_bf16.h>

// TensorDLT: closed-form 4-point homography (Heckbert square->quad) instead of
// per-batch 8x8 LU solve. Source corners fixed at (0,0),(127,0),(127,127),(0,127).
// offset[b, 8] = (du1,dv1,du2,dv2,du3,dv3,du4,dv4) scaled by MAX_PERTURBATION=32.
// Output H[b,3,3] row-major with H[2][2]=1 (matches reference h8=1 convention).
//
// R1 counters: kernel itself <43us (not in top-5; harness 268MB d_ws poison fills
// dominate at ~44us each). This revision: single-tile blocks (no grid-stride
// loop), float4 LDS->global stores (2.25 st/thread vs 9 scalar).

#define THREADS 256

__global__ __launch_bounds__(THREADS) void dlt_kernel(
    const float* __restrict__ off, float* __restrict__ out, int B) {
    __shared__ float lds[THREADS * 9];   // 9216 B; stride-9 writes: <=2 lanes/bank
    const int tid = threadIdx.x;
    const int base = blockIdx.x * THREADS;
    const int i = base + tid;

    float h[9];
    if (i < B) {
        // two float4 loads cover the 8 offsets (32B per item, 16B aligned)
        const float4* p = (const float4*)off + (size_t)i * 2;
        const float4 o0 = p[0];
        const float4 o1 = p[1];
        const float M = 32.0f;
        // destination corners (x_k, y_k) for src (0,0),(127,0),(127,127),(0,127)
        const float x0 = 0.0f   + M * o0.x, y0 = 0.0f   + M * o0.y;
        const float x1 = 127.0f + M * o0.z, y1 = 0.0f   + M * o0.w;
        const float x2 = 127.0f + M * o1.x, y2 = 127.0f + M * o1.y;
        const float x3 = 0.0f   + M * o1.z, y3 = 127.0f + M * o1.w;

        // Heckbert: unit square (0,0),(1,0),(1,1),(0,1) -> (x0..x3, y0..y3)
        const float sx  = x0 - x1 + x2 - x3;
        const float sy  = y0 - y1 + y2 - y3;
        const float dx1 = x1 - x2, dy1 = y1 - y2;
        const float dx2 = x3 - x2, dy2 = y3 - y2;
        const float inv = 1.0f / (dx1 * dy2 - dy1 * dx2);  // |den| >= ~9000, safe
        const float g  = (sx * dy2 - sy * dx2) * inv;
        const float hh = (sy * dx1 - sx * dy1) * inv;
        const float a = x1 - x0 + g  * x1;
        const float b = x3 - x0 + hh * x3;
        const float d = y1 - y0 + g  * y1;
        const float e = y3 - y0 + hh * y3;

        // compose with src scaling diag(1/127, 1/127, 1): scale cols 0,1
        const float s = 1.0f / 127.0f;
        h[0] = a  * s;  h[1] = b  * s;  h[2] = x0;
        h[3] = d  * s;  h[4] = e  * s;  h[5] = y0;
        h[6] = g  * s;  h[7] = hh * s;  h[8] = 1.0f;
    } else {
        #pragma unroll
        for (int k = 0; k < 9; ++k) h[k] = 0.0f;
    }

    #pragma unroll
    for (int k = 0; k < 9; ++k) lds[tid * 9 + k] = h[k];
    __syncthreads();

    // coalesced float4 stores of the block's contiguous 2304 floats (576 f4)
    const int nitems = (B - base < THREADS) ? (B - base) : THREADS;
    const int nvec = (nitems * 9) / 4;           // full float4s
    float4* ovec = (float4*)(out + (size_t)base * 9);
    const float4* lvec = (const float4*)lds;
    for (int k = tid; k < nvec; k += THREADS) {
        ovec[k] = lvec[k];
    }
    // tail (only when nitems*9 % 4 != 0; for full 256-item blocks 2304%4==0)
    const int tail = nitems * 9 - nvec * 4;
    if (tid < tail) {
        out[(size_t)base * 9 + nvec * 4 + tid] = lds[nvec * 4 + tid];
    }
}

extern "C" void kernel_launch(void* const* d_in, const int* in_sizes, int n_in,
                              void* d_out, int out_size, void* d_ws, size_t ws_size,
                              hipStream_t stream) {
    const float* off = (const float*)d_in[0];
    float* out = (float*)d_out;
    const int B = in_sizes[0] / 8;              // 524288
    const int blocks = (B + THREADS - 1) / THREADS;  // 2048 -> 8 blocks/CU
    dlt_kernel<<<blocks, THREADS, 0, stream>>>(off, out, B);
}